// Round 3
// baseline (4437.156 us; speedup 1.0000x reference)
//
#include <hip/hip_runtime.h>
#include <stdint.h>

// ---------------------------------------------------------------------------
// Net_27891517620298: edge-popup supermask CNN forward, fp32 baseline.
// Pipeline: [radix-select thresholds for 5 score tensors] -> [mask weights]
//           -> conv1 (s1) -> conv2 (s2) -> conv3 (s2, fused global-avg-pool)
//           -> fc1 (relu) -> fc2.
// ---------------------------------------------------------------------------

// score tensor element counts, cumulative boundaries
constexpr unsigned CUM0 = 3456u;      // s1: 128*3*3*3
constexpr unsigned CUM1 = 298368u;    // + s2: 256*128*3*3
constexpr unsigned CUM2 = 1478016u;   // + s3: 512*256*3*3
constexpr unsigned CUM3 = 2002304u;   // + fs1: 1024*512
constexpr unsigned STOT = 2012544u;   // + fs2: 10*1024

__device__ __forceinline__ int find_tensor(unsigned idx, unsigned& li) {
    if (idx < CUM0) { li = idx;        return 0; }
    if (idx < CUM1) { li = idx - CUM0; return 1; }
    if (idx < CUM2) { li = idx - CUM1; return 2; }
    if (idx < CUM3) { li = idx - CUM2; return 3; }
    li = idx - CUM3; return 4;
}

// Pass 1: histogram of top 16 bits of |score| bit-pattern (uint order == float
// order for non-negative floats).
__global__ void hist_pass1(const float* __restrict__ s0, const float* __restrict__ s1,
                           const float* __restrict__ s2, const float* __restrict__ s3,
                           const float* __restrict__ s4, unsigned* __restrict__ hist) {
    unsigned idx = blockIdx.x * 256u + threadIdx.x;
    if (idx >= STOT) return;
    unsigned li; int t = find_tensor(idx, li);
    const float* sp = t == 0 ? s0 : t == 1 ? s1 : t == 2 ? s2 : t == 3 ? s3 : s4;
    unsigned key = __float_as_uint(sp[li]) & 0x7fffffffu;
    atomicAdd(&hist[(unsigned)t * 65536u + (key >> 16)], 1u);
}

// Pass 2: histogram of low 16 bits, only for elements in the selected top bin.
__global__ void hist_pass2(const float* __restrict__ s0, const float* __restrict__ s1,
                           const float* __restrict__ s2, const float* __restrict__ s3,
                           const float* __restrict__ s4, const unsigned* __restrict__ selBin,
                           unsigned* __restrict__ hist) {
    unsigned idx = blockIdx.x * 256u + threadIdx.x;
    if (idx >= STOT) return;
    unsigned li; int t = find_tensor(idx, li);
    const float* sp = t == 0 ? s0 : t == 1 ? s1 : t == 2 ? s2 : t == 3 ? s3 : s4;
    unsigned key = __float_as_uint(sp[li]) & 0x7fffffffu;
    if ((key >> 16) == selBin[t])
        atomicAdd(&hist[(unsigned)t * 65536u + (key & 0xffffu)], 1u);
}

// Find bin containing sorted position `target` (0-indexed ascending) in a
// 65536-bin histogram. pass==0: target=n/2, writes selBin+rloc.
// pass==1: target=rloc, combines into final threshold T=(selBin<<16)|bin.
__global__ void radix_find(const unsigned* __restrict__ hist, unsigned* __restrict__ selBin,
                           unsigned* __restrict__ rloc, unsigned* __restrict__ T, int pass) {
    const int t = blockIdx.x;
    const int tid = threadIdx.x;
    unsigned n = t == 0 ? 3456u : t == 1 ? 294912u : t == 2 ? 1179648u : t == 3 ? 524288u : 10240u;
    unsigned target = (pass == 0) ? (n >> 1) : rloc[t];
    const unsigned* h = hist + (size_t)t * 65536u;
    __shared__ unsigned part[256];
    __shared__ unsigned sq, sbelow;
    unsigned s = 0;
    const uint4* h4 = (const uint4*)(h + (size_t)tid * 256u);
    for (int i = 0; i < 64; i++) { uint4 v = h4[i]; s += v.x + v.y + v.z + v.w; }
    part[tid] = s;
    __syncthreads();
    if (tid == 0) {
        unsigned cum = 0; int q = 0;
        for (; q < 256; q++) { unsigned c = part[q]; if (cum + c > target) break; cum += c; }
        sq = (unsigned)q; sbelow = cum;
    }
    __syncthreads();
    unsigned q = sq, below = sbelow;
    part[tid] = h[q * 256u + tid];
    __syncthreads();
    if (tid == 0) {
        unsigned cum = below; int b = 0;
        for (; b < 256; b++) { unsigned c = part[b]; if (cum + c > target) break; cum += c; }
        unsigned bin = q * 256u + (unsigned)b;
        if (pass == 0) { selBin[t] = bin; rloc[t] = target - cum; }
        else           { T[t] = (selBin[t] << 16) | bin; }
    }
}

// wm = (|s| bits >= T) ? w : 0  for all 5 weight tensors
__global__ void mask_weights(const float* __restrict__ w0, const float* __restrict__ w1,
                             const float* __restrict__ w2, const float* __restrict__ w3,
                             const float* __restrict__ w4,
                             const float* __restrict__ s0, const float* __restrict__ s1,
                             const float* __restrict__ s2, const float* __restrict__ s3,
                             const float* __restrict__ s4,
                             const unsigned* __restrict__ T,
                             float* __restrict__ m0, float* __restrict__ m1,
                             float* __restrict__ m2, float* __restrict__ m3,
                             float* __restrict__ m4) {
    unsigned idx = blockIdx.x * 256u + threadIdx.x;
    if (idx >= STOT) return;
    unsigned li; int t = find_tensor(idx, li);
    const float* sp = t == 0 ? s0 : t == 1 ? s1 : t == 2 ? s2 : t == 3 ? s3 : s4;
    const float* wp = t == 0 ? w0 : t == 1 ? w1 : t == 2 ? w2 : t == 3 ? w3 : w4;
    float*       mp = t == 0 ? m0 : t == 1 ? m1 : t == 2 ? m2 : t == 3 ? m3 : m4;
    unsigned key = __float_as_uint(sp[li]) & 0x7fffffffu;
    mp[li] = (key >= T[t]) ? wp[li] : 0.f;
}

// ---------------------------------------------------------------------------
// Direct 3x3 conv, pad 1, stride S. Each thread computes 2x2 output pixels
// for KT output channels. Block = TX*TY threads covering a (2TX)x(2TY) output
// tile. POOL fuses global average pooling (tile must cover whole output).
// ---------------------------------------------------------------------------
template <int C, int H, int W, int K, int S, int TX, int TY, int KT, bool POOL>
__global__ __launch_bounds__(TX* TY) void conv3x3(const float* __restrict__ in,
                                                  const float* __restrict__ wm,
                                                  const float* __restrict__ bias,
                                                  float* __restrict__ out) {
    constexpr int OH = H / S, OW = W / S;
    constexpr int TILW = TX * 2, TILH = TY * 2;
    constexpr int ITW = (TILW - 1) * S + 3;
    constexpr int ITH = (TILH - 1) * S + 3;
    constexpr int NTHREADS = TX * TY;
    constexpr int NLOAD = (ITH * ITW + NTHREADS - 1) / NTHREADS;
    constexpr int KG = K / KT;

    __shared__ float sIn[ITH * ITW];
    __shared__ float sW[9 * KT];

    const int tid = threadIdx.x;
    const int tx = tid % TX, ty = tid / TX;
    const int kg = blockIdx.z % KG, n = blockIdx.z / KG;
    const int ox0 = blockIdx.x * TILW, oy0 = blockIdx.y * TILH;
    const int ix0 = ox0 * S - 1, iy0 = oy0 * S - 1;

    const float* inN = in + (size_t)n * C * H * W;
    const float* wkg = wm + (size_t)kg * KT * C * 9;

    // precompute staging offsets (same for every c; -1 = zero pad, -2 = skip)
    int goff[NLOAD];
    #pragma unroll
    for (int i = 0; i < NLOAD; i++) {
        int idx = tid + i * NTHREADS;
        if (idx < ITH * ITW) {
            int r = idx / ITW, col = idx % ITW;
            int gy = iy0 + r, gx = ix0 + col;
            goff[i] = (gy >= 0 && gy < H && gx >= 0 && gx < W) ? (gy * W + gx) : -1;
        } else goff[i] = -2;
    }

    float acc[2][2][KT];
    #pragma unroll
    for (int py = 0; py < 2; py++)
        #pragma unroll
        for (int px = 0; px < 2; px++)
            #pragma unroll
            for (int j = 0; j < KT; j++) acc[py][px][j] = 0.f;

    for (int c = 0; c < C; c++) {
        const float* inC = inN + (size_t)c * H * W;
        #pragma unroll
        for (int i = 0; i < NLOAD; i++) {
            int g = goff[i];
            if (g >= -1) sIn[tid + i * NTHREADS] = (g >= 0) ? inC[g] : 0.f;
        }
        // stage 9*KT weights; strided so it works for any NTHREADS (conv3 has 64)
        for (int i = tid; i < 9 * KT; i += NTHREADS) {
            int e = i / KT, j = i % KT;
            sW[i] = wkg[j * C * 9 + c * 9 + e];
        }
        __syncthreads();

        float vin[S + 3][S + 3];
        const float* base = &sIn[(ty * 2 * S) * ITW + tx * 2 * S];
        #pragma unroll
        for (int r = 0; r < S + 3; r++)
            #pragma unroll
            for (int cc = 0; cc < S + 3; cc++) vin[r][cc] = base[r * ITW + cc];

        #pragma unroll
        for (int e = 0; e < 9; e++) {
            const int dy = e / 3, dx = e % 3;
            #pragma unroll
            for (int j = 0; j < KT; j++) {
                float wv = sW[e * KT + j];
                #pragma unroll
                for (int py = 0; py < 2; py++)
                    #pragma unroll
                    for (int px = 0; px < 2; px++)
                        acc[py][px][j] = fmaf(vin[py * S + dy][px * S + dx], wv, acc[py][px][j]);
            }
        }
        __syncthreads();
    }

    if (!POOL) {
        #pragma unroll
        for (int j = 0; j < KT; j++) {
            float b = bias[kg * KT + j];
            #pragma unroll
            for (int py = 0; py < 2; py++)
                #pragma unroll
                for (int px = 0; px < 2; px++) {
                    int oy = oy0 + ty * 2 + py, ox = ox0 + tx * 2 + px;
                    float v = acc[py][px][j] + b;
                    v = v > 0.f ? v : 0.f;
                    out[(((size_t)n * K + kg * KT + j) * OH + oy) * OW + ox] = v;
                }
        }
    } else {
        // fused global average pool; block must be one wave (TX*TY==64)
        #pragma unroll
        for (int j = 0; j < KT; j++) {
            float b = bias[kg * KT + j];
            float sum = 0.f;
            #pragma unroll
            for (int py = 0; py < 2; py++)
                #pragma unroll
                for (int px = 0; px < 2; px++) {
                    float v = acc[py][px][j] + b;
                    sum += v > 0.f ? v : 0.f;
                }
            for (int off = 32; off > 0; off >>= 1) sum += __shfl_down(sum, off);
            if (tid == 0) out[(size_t)n * K + kg * KT + j] = sum * (1.f / (OH * OW));
        }
    }
}

// fc1: out[n][o] = relu(pooled[n][:] . w[o][:] + b[o]), n=64, o=1024, c=512
__global__ void fc1_kernel(const float* __restrict__ pooled, const float* __restrict__ w,
                           const float* __restrict__ b, float* __restrict__ out) {
    int t = blockIdx.x * 256 + threadIdx.x;  // 65536 threads
    int o = t & 1023, n = t >> 10;
    const float4* w4 = (const float4*)(w + (size_t)o * 512);
    const float4* p4 = (const float4*)(pooled + (size_t)n * 512);
    float acc = 0.f;
    for (int i = 0; i < 128; i++) {
        float4 a = p4[i], ww = w4[i];
        acc += a.x * ww.x + a.y * ww.y + a.z * ww.z + a.w * ww.w;
    }
    acc += b[o];
    out[t] = acc > 0.f ? acc : 0.f;
}

// fc2: out[n][o] = h[n][:] . w[o][:] + b[o], n=64, o=10, c=1024. Block per n.
__global__ void fc2_kernel(const float* __restrict__ h, const float* __restrict__ w,
                           const float* __restrict__ b, float* __restrict__ out) {
    int n = blockIdx.x, tid = threadIdx.x;
    __shared__ float redw[40];
    const float4* h4 = (const float4*)(h + (size_t)n * 1024);
    float4 a = h4[tid];  // exactly one float4 per thread
    for (int o = 0; o < 10; o++) {
        const float4* w4 = (const float4*)(w + (size_t)o * 1024);
        float4 ww = w4[tid];
        float v = a.x * ww.x + a.y * ww.y + a.z * ww.z + a.w * ww.w;
        for (int off = 32; off > 0; off >>= 1) v += __shfl_down(v, off);
        if ((tid & 63) == 0) redw[o * 4 + (tid >> 6)] = v;
    }
    __syncthreads();
    if (tid < 10) {
        float s = redw[tid * 4] + redw[tid * 4 + 1] + redw[tid * 4 + 2] + redw[tid * 4 + 3] + b[tid];
        out[n * 10 + tid] = s;
    }
}

extern "C" void kernel_launch(void* const* d_in, const int* in_sizes, int n_in,
                              void* d_out, int out_size, void* d_ws, size_t ws_size,
                              hipStream_t stream) {
    const float* x   = (const float*)d_in[0];
    const float* w1  = (const float*)d_in[1];
    const float* s1  = (const float*)d_in[2];
    const float* b1  = (const float*)d_in[3];
    const float* w2  = (const float*)d_in[4];
    const float* s2  = (const float*)d_in[5];
    const float* b2  = (const float*)d_in[6];
    const float* w3  = (const float*)d_in[7];
    const float* s3  = (const float*)d_in[8];
    const float* b3  = (const float*)d_in[9];
    const float* fw1 = (const float*)d_in[10];
    const float* fs1 = (const float*)d_in[11];
    const float* fb1 = (const float*)d_in[12];
    const float* fw2 = (const float*)d_in[13];
    const float* fs2 = (const float*)d_in[14];
    const float* fb2 = (const float*)d_in[15];
    float* out = (float*)d_out;

    char* ws = (char*)d_ws;
    size_t off = 0;
    auto alloc = [&](size_t bytes) -> char* {
        char* p = ws + off;
        off = (off + bytes + 255) & ~(size_t)255;
        return p;
    };
    unsigned* hist   = (unsigned*)alloc(2ull * 5 * 65536 * 4);  // histA + histB
    unsigned* histB  = hist + 5 * 65536;
    unsigned* selBin = (unsigned*)alloc(64);
    unsigned* rloc   = (unsigned*)alloc(64);
    unsigned* T      = (unsigned*)alloc(64);
    float* wm1  = (float*)alloc(3456ull * 4);
    float* wm2  = (float*)alloc(294912ull * 4);
    float* wm3  = (float*)alloc(1179648ull * 4);
    float* fwm1 = (float*)alloc(524288ull * 4);
    float* fwm2 = (float*)alloc(10240ull * 4);
    float* h1   = (float*)alloc(33554432ull * 4);  // 64x128x64x64
    float* h2   = (float*)alloc(16777216ull * 4);  // 64x256x32x32
    float* pooled = (float*)alloc(32768ull * 4);   // 64x512
    float* fc1h   = (float*)alloc(65536ull * 4);   // 64x1024
    if (off > ws_size) return;  // workspace too small -> visible failure

    (void)hipMemsetAsync(hist, 0, 2ull * 5 * 65536 * 4, stream);
    int gs = (STOT + 255) / 256;
    hist_pass1<<<gs, 256, 0, stream>>>(s1, s2, s3, fs1, fs2, hist);
    radix_find<<<5, 256, 0, stream>>>(hist, selBin, rloc, T, 0);
    hist_pass2<<<gs, 256, 0, stream>>>(s1, s2, s3, fs1, fs2, selBin, histB);
    radix_find<<<5, 256, 0, stream>>>(histB, selBin, rloc, T, 1);
    mask_weights<<<gs, 256, 0, stream>>>(w1, w2, w3, fw1, fw2, s1, s2, s3, fs1, fs2, T,
                                         wm1, wm2, wm3, fwm1, fwm2);

    // conv1: 3->128, 64x64, s1. tiles 32x32, grid (2,2, 64*16)
    conv3x3<3, 64, 64, 128, 1, 16, 16, 8, false>
        <<<dim3(2, 2, 64 * 16), 256, 0, stream>>>(x, wm1, b1, h1);
    // conv2: 128->256, 64x64 -> 32x32, s2. one 32x32 tile, grid (1,1, 64*32)
    conv3x3<128, 64, 64, 256, 2, 16, 16, 8, false>
        <<<dim3(1, 1, 64 * 32), 256, 0, stream>>>(h1, wm2, b2, h2);
    // conv3: 256->512, 32x32 -> 16x16, s2, fused GAP. 64-thread blocks, grid (1,1, 64*64)
    conv3x3<256, 32, 32, 512, 2, 8, 8, 8, true>
        <<<dim3(1, 1, 64 * 64), 64, 0, stream>>>(h2, wm3, b3, pooled);

    fc1_kernel<<<256, 256, 0, stream>>>(pooled, fwm1, fb1, fc1h);
    fc2_kernel<<<64, 256, 0, stream>>>(fc1h, fwm2, fb2, out);
}

// Round 4
// 947.833 us; speedup vs baseline: 4.6814x; 4.6814x over previous
//
#include <hip/hip_runtime.h>
#include <stdint.h>

// ---------------------------------------------------------------------------
// Net_27891517620298: edge-popup supermask CNN forward.
// R3: conv2/conv3 as bf16 implicit-GEMM on MFMA 16x16x32; bf16 intermediates.
// Pipeline: radix-select thresholds -> mask weights -> reorder w2/w3 to
// bf16 [e][k][c] -> conv1 (direct fp32->bf16) -> conv2 (MFMA) ->
// conv3 (MFMA + fused GAP, fp32 atomics) -> fc1 -> fc2.
// ---------------------------------------------------------------------------

typedef __attribute__((ext_vector_type(8))) short short8;
typedef __attribute__((ext_vector_type(4))) float floatx4;

__device__ __forceinline__ unsigned short f2bf(float f) {
    unsigned u = __float_as_uint(f);
    u += 0x7fffu + ((u >> 16) & 1u);   // round-to-nearest-even
    return (unsigned short)(u >> 16);
}

// ---------------- top-k selection (exact, 2-pass radix on |score| bits) -----
constexpr unsigned CUM0 = 3456u;
constexpr unsigned CUM1 = 298368u;
constexpr unsigned CUM2 = 1478016u;
constexpr unsigned CUM3 = 2002304u;
constexpr unsigned STOT = 2012544u;

__device__ __forceinline__ int find_tensor(unsigned idx, unsigned& li) {
    if (idx < CUM0) { li = idx;        return 0; }
    if (idx < CUM1) { li = idx - CUM0; return 1; }
    if (idx < CUM2) { li = idx - CUM1; return 2; }
    if (idx < CUM3) { li = idx - CUM2; return 3; }
    li = idx - CUM3; return 4;
}

__global__ void hist_pass1(const float* __restrict__ s0, const float* __restrict__ s1,
                           const float* __restrict__ s2, const float* __restrict__ s3,
                           const float* __restrict__ s4, unsigned* __restrict__ hist) {
    unsigned idx = blockIdx.x * 256u + threadIdx.x;
    if (idx >= STOT) return;
    unsigned li; int t = find_tensor(idx, li);
    const float* sp = t == 0 ? s0 : t == 1 ? s1 : t == 2 ? s2 : t == 3 ? s3 : s4;
    unsigned key = __float_as_uint(sp[li]) & 0x7fffffffu;
    atomicAdd(&hist[(unsigned)t * 65536u + (key >> 16)], 1u);
}

__global__ void hist_pass2(const float* __restrict__ s0, const float* __restrict__ s1,
                           const float* __restrict__ s2, const float* __restrict__ s3,
                           const float* __restrict__ s4, const unsigned* __restrict__ selBin,
                           unsigned* __restrict__ hist) {
    unsigned idx = blockIdx.x * 256u + threadIdx.x;
    if (idx >= STOT) return;
    unsigned li; int t = find_tensor(idx, li);
    const float* sp = t == 0 ? s0 : t == 1 ? s1 : t == 2 ? s2 : t == 3 ? s3 : s4;
    unsigned key = __float_as_uint(sp[li]) & 0x7fffffffu;
    if ((key >> 16) == selBin[t])
        atomicAdd(&hist[(unsigned)t * 65536u + (key & 0xffffu)], 1u);
}

__global__ void radix_find(const unsigned* __restrict__ hist, unsigned* __restrict__ selBin,
                           unsigned* __restrict__ rloc, unsigned* __restrict__ T, int pass) {
    const int t = blockIdx.x;
    const int tid = threadIdx.x;
    unsigned n = t == 0 ? 3456u : t == 1 ? 294912u : t == 2 ? 1179648u : t == 3 ? 524288u : 10240u;
    unsigned target = (pass == 0) ? (n >> 1) : rloc[t];
    const unsigned* h = hist + (size_t)t * 65536u;
    __shared__ unsigned part[256];
    __shared__ unsigned sq, sbelow;
    unsigned s = 0;
    const uint4* h4 = (const uint4*)(h + (size_t)tid * 256u);
    for (int i = 0; i < 64; i++) { uint4 v = h4[i]; s += v.x + v.y + v.z + v.w; }
    part[tid] = s;
    __syncthreads();
    if (tid == 0) {
        unsigned cum = 0; int q = 0;
        for (; q < 256; q++) { unsigned c = part[q]; if (cum + c > target) break; cum += c; }
        sq = (unsigned)q; sbelow = cum;
    }
    __syncthreads();
    unsigned q = sq, below = sbelow;
    part[tid] = h[q * 256u + tid];
    __syncthreads();
    if (tid == 0) {
        unsigned cum = below; int b = 0;
        for (; b < 256; b++) { unsigned c = part[b]; if (cum + c > target) break; cum += c; }
        unsigned bin = q * 256u + (unsigned)b;
        if (pass == 0) { selBin[t] = bin; rloc[t] = target - cum; }
        else           { T[t] = (selBin[t] << 16) | bin; }
    }
}

__global__ void mask_weights(const float* __restrict__ w0, const float* __restrict__ w1,
                             const float* __restrict__ w2, const float* __restrict__ w3,
                             const float* __restrict__ w4,
                             const float* __restrict__ s0, const float* __restrict__ s1,
                             const float* __restrict__ s2, const float* __restrict__ s3,
                             const float* __restrict__ s4,
                             const unsigned* __restrict__ T,
                             float* __restrict__ m0, float* __restrict__ m1,
                             float* __restrict__ m2, float* __restrict__ m3,
                             float* __restrict__ m4) {
    unsigned idx = blockIdx.x * 256u + threadIdx.x;
    if (idx >= STOT) return;
    unsigned li; int t = find_tensor(idx, li);
    const float* sp = t == 0 ? s0 : t == 1 ? s1 : t == 2 ? s2 : t == 3 ? s3 : s4;
    const float* wp = t == 0 ? w0 : t == 1 ? w1 : t == 2 ? w2 : t == 3 ? w3 : w4;
    float*       mp = t == 0 ? m0 : t == 1 ? m1 : t == 2 ? m2 : t == 3 ? m3 : m4;
    unsigned key = __float_as_uint(sp[li]) & 0x7fffffffu;
    mp[li] = (key >= T[t]) ? wp[li] : 0.f;
}

// reorder masked fp32 weights [k][c][3][3] -> bf16 A[e][k][c]
template <int KOUT, int CIN>
__global__ void reorder_w(const float* __restrict__ wm, unsigned short* __restrict__ A) {
    int t = blockIdx.x * 256 + threadIdx.x;
    if (t >= KOUT * CIN) return;
    int k = t / CIN, c = t % CIN;
    #pragma unroll
    for (int e = 0; e < 9; e++)
        A[((size_t)e * KOUT + k) * CIN + c] = f2bf(wm[(size_t)t * 9 + e]);
}

// ---------------- conv1: direct 3x3 fp32, bf16 output -----------------------
template <int C, int H, int W, int K, int TX, int TY, int KT>
__global__ __launch_bounds__(TX* TY) void conv_direct(const float* __restrict__ in,
                                                      const float* __restrict__ wm,
                                                      const float* __restrict__ bias,
                                                      unsigned short* __restrict__ out) {
    constexpr int TILW = TX * 2, TILH = TY * 2;
    constexpr int ITW = TILW + 2, ITH = TILH + 2;
    constexpr int NTHREADS = TX * TY;
    constexpr int NLOAD = (ITH * ITW + NTHREADS - 1) / NTHREADS;
    constexpr int KG = K / KT;

    __shared__ float sIn[ITH * ITW];
    __shared__ float sW[9 * KT];

    const int tid = threadIdx.x;
    const int tx = tid % TX, ty = tid / TX;
    const int kg = blockIdx.z % KG, n = blockIdx.z / KG;
    const int ox0 = blockIdx.x * TILW, oy0 = blockIdx.y * TILH;
    const int ix0 = ox0 - 1, iy0 = oy0 - 1;

    const float* inN = in + (size_t)n * C * H * W;
    const float* wkg = wm + (size_t)kg * KT * C * 9;

    int goff[NLOAD];
    #pragma unroll
    for (int i = 0; i < NLOAD; i++) {
        int idx = tid + i * NTHREADS;
        if (idx < ITH * ITW) {
            int r = idx / ITW, col = idx % ITW;
            int gy = iy0 + r, gx = ix0 + col;
            goff[i] = (gy >= 0 && gy < H && gx >= 0 && gx < W) ? (gy * W + gx) : -1;
        } else goff[i] = -2;
    }

    float acc[2][2][KT];
    #pragma unroll
    for (int py = 0; py < 2; py++)
        #pragma unroll
        for (int px = 0; px < 2; px++)
            #pragma unroll
            for (int j = 0; j < KT; j++) acc[py][px][j] = 0.f;

    for (int c = 0; c < C; c++) {
        const float* inC = inN + (size_t)c * H * W;
        #pragma unroll
        for (int i = 0; i < NLOAD; i++) {
            int g = goff[i];
            if (g >= -1) sIn[tid + i * NTHREADS] = (g >= 0) ? inC[g] : 0.f;
        }
        for (int i = tid; i < 9 * KT; i += NTHREADS) {
            int e = i / KT, j = i % KT;
            sW[i] = wkg[j * C * 9 + c * 9 + e];
        }
        __syncthreads();

        float vin[4][4];
        const float* base = &sIn[(ty * 2) * ITW + tx * 2];
        #pragma unroll
        for (int r = 0; r < 4; r++)
            #pragma unroll
            for (int cc = 0; cc < 4; cc++) vin[r][cc] = base[r * ITW + cc];

        #pragma unroll
        for (int e = 0; e < 9; e++) {
            const int dy = e / 3, dx = e % 3;
            #pragma unroll
            for (int j = 0; j < KT; j++) {
                float wv = sW[e * KT + j];
                #pragma unroll
                for (int py = 0; py < 2; py++)
                    #pragma unroll
                    for (int px = 0; px < 2; px++)
                        acc[py][px][j] = fmaf(vin[py + dy][px + dx], wv, acc[py][px][j]);
            }
        }
        __syncthreads();
    }

    #pragma unroll
    for (int j = 0; j < KT; j++) {
        float b = bias[kg * KT + j];
        #pragma unroll
        for (int py = 0; py < 2; py++)
            #pragma unroll
            for (int px = 0; px < 2; px++) {
                int oy = oy0 + ty * 2 + py, ox = ox0 + tx * 2 + px;
                float v = acc[py][px][j] + b;
                v = v > 0.f ? v : 0.f;
                out[(((size_t)n * K + kg * KT + j) * H + oy) * W + ox] = f2bf(v);
            }
    }
}

// ---------------- conv2/conv3: bf16 implicit GEMM on MFMA 16x16x32 ----------
// stride-2 3x3 conv. Block = 256 thr (4 waves). Output tile: 128 k x 128 pixels
// (TOY x TOX rows/cols). K-loop: c in chunks of 32 (LDS input tile, e-invariant)
// x 9 taps. LDS rows padded to 80 B. POOL fuses global-avg-pool via atomics.
template <int C, int H, int W, int KOUT, int TOY, int TOX, bool POOL>
__global__ __launch_bounds__(256) void conv_mfma(const unsigned short* __restrict__ in,
                                                 const unsigned short* __restrict__ A,
                                                 const float* __restrict__ bias,
                                                 void* __restrict__ outv) {
    constexpr int OH = H / 2, OW = W / 2;
    constexpr int RH = 2 * TOY + 1, IW = 2 * TOX + 1;
    constexpr int HWv = H * W;
    constexpr int NC = C / 32;
    constexpr int NSLOT = RH * IW * 4;          // (c8, iy, ix) staging slots
    constexpr int SLMAX = (NSLOT + 255) / 256;

    __shared__ unsigned short sIn[RH * IW * 40];  // [iy][ix][c(32)+pad8], 16B units
    __shared__ unsigned short sWt[128 * 40];      // [k(128)][c(32)+pad8]

    const int tid = threadIdx.x;
    const int lane = tid & 63;
    const int wv = tid >> 6;
    const int l15 = lane & 15;
    const int quad = lane >> 4;
    const int pt = blockIdx.x, kb = blockIdx.y, n = blockIdx.z;
    const int k0 = kb * 128;
    const int oy0 = pt * TOY;
    const int g0y = 2 * oy0 - 1;

    // per-thread staging slots (chunk-invariant): slot s = (c8*RH + iy)*IW + ix
    int soff[SLMAX], slds[SLMAX];
    #pragma unroll
    for (int i = 0; i < SLMAX; i++) {
        int s = tid + i * 256;
        if (s < NSLOT) {
            int ix = s % IW; int t2 = s / IW; int iy = t2 % RH; int c8 = t2 / RH;
            int gy = g0y + iy, gx = ix - 1;   // gx max = 2*TOX-1 = W-1, always valid
            slds[i] = (iy * IW + ix) * 40 + c8 * 8;
            soff[i] = (gy >= 0 && gy < H && gx >= 0) ? (c8 * 8 * HWv + gy * W + gx) : -1;
        } else { soff[i] = -2; slds[i] = 0; }
    }

    // B-frag pixel bases (pixel p = fn*16 + l15 -> (oyl, oxl))
    int pB[8];
    #pragma unroll
    for (int fn = 0; fn < 8; fn++) {
        int p = fn * 16 + l15;
        int oyl = p / TOX, oxl = p % TOX;
        pB[fn] = (oyl * 2 * IW + oxl * 2) * 40 + quad * 8;
    }
    const int mw = wv * 32;   // wave's 32 output-channel rows

    floatx4 acc[2][8];
    #pragma unroll
    for (int fm = 0; fm < 2; fm++)
        #pragma unroll
        for (int fn = 0; fn < 8; fn++) acc[fm][fn] = (floatx4){0.f, 0.f, 0.f, 0.f};

    const int inN = n * C * HWv;

    for (int cc = 0; cc < NC; cc++) {
        __syncthreads();   // protect sIn from previous iteration's readers
        const int cbase = inN + cc * 32 * HWv;
        #pragma unroll
        for (int i = 0; i < SLMAX; i++) {
            int so = soff[i];
            if (so >= 0) {
                short8 v;
                #pragma unroll
                for (int j = 0; j < 8; j++) v[j] = (short)in[cbase + so + j * HWv];
                *(short8*)&sIn[slds[i]] = v;
            } else if (so == -1 && cc == 0) {
                *(short8*)&sIn[slds[i]] = (short8){0, 0, 0, 0, 0, 0, 0, 0};  // pad rows, once
            }
        }
        for (int e = 0; e < 9; e++) {
            __syncthreads();   // sWt reuse; on e==0 also covers sIn staging
            {
                const unsigned short* src = A + ((size_t)e * KOUT + k0) * C + cc * 32;
                #pragma unroll
                for (int i = 0; i < 2; i++) {
                    int s = tid + i * 256;
                    int k = s >> 2, c8 = s & 3;
                    short8 v = *(const short8*)(src + k * C + c8 * 8);
                    *(short8*)&sWt[k * 40 + c8 * 8] = v;
                }
            }
            __syncthreads();
            const int dy = e / 3, dx = e - dy * 3;
            const int boff = (dy * IW + dx) * 40;
            short8 afr[2], bfr[8];
            #pragma unroll
            for (int fm = 0; fm < 2; fm++)
                afr[fm] = *(const short8*)&sWt[(mw + fm * 16 + l15) * 40 + quad * 8];
            #pragma unroll
            for (int fn = 0; fn < 8; fn++)
                bfr[fn] = *(const short8*)&sIn[pB[fn] + boff];
            #pragma unroll
            for (int fm = 0; fm < 2; fm++)
                #pragma unroll
                for (int fn = 0; fn < 8; fn++)
                    acc[fm][fn] = __builtin_amdgcn_mfma_f32_16x16x32_bf16(
                        afr[fm], bfr[fn], acc[fm][fn], 0, 0, 0);
        }
    }

    if (!POOL) {
        unsigned short* out = (unsigned short*)outv;
        #pragma unroll
        for (int fm = 0; fm < 2; fm++) {
            #pragma unroll
            for (int reg = 0; reg < 4; reg++) {
                int k = k0 + mw + fm * 16 + quad * 4 + reg;
                float b = bias[k];
                #pragma unroll
                for (int fn = 0; fn < 8; fn++) {
                    int p = fn * 16 + l15;
                    int oy = oy0 + p / TOX, ox = p % TOX;
                    float v = acc[fm][fn][reg] + b;
                    v = v > 0.f ? v : 0.f;
                    out[((size_t)(n * KOUT + k) * OH + oy) * OW + ox] = f2bf(v);
                }
            }
        }
    } else {
        float* out = (float*)outv;
        #pragma unroll
        for (int fm = 0; fm < 2; fm++) {
            #pragma unroll
            for (int reg = 0; reg < 4; reg++) {
                int k = k0 + mw + fm * 16 + quad * 4 + reg;
                float b = bias[k];
                float s = 0.f;
                #pragma unroll
                for (int fn = 0; fn < 8; fn++) {
                    float v = acc[fm][fn][reg] + b;
                    s += v > 0.f ? v : 0.f;
                }
                s += __shfl_xor(s, 1); s += __shfl_xor(s, 2);
                s += __shfl_xor(s, 4); s += __shfl_xor(s, 8);
                if (l15 == 0) atomicAdd(&out[n * KOUT + k], s * (1.0f / (OH * OW)));
            }
        }
    }
}

// ---------------- FCs (fp32, tiny) -----------------------------------------
__global__ void fc1_kernel(const float* __restrict__ pooled, const float* __restrict__ w,
                           const float* __restrict__ b, float* __restrict__ out) {
    int t = blockIdx.x * 256 + threadIdx.x;
    int o = t & 1023, n = t >> 10;
    const float4* w4 = (const float4*)(w + (size_t)o * 512);
    const float4* p4 = (const float4*)(pooled + (size_t)n * 512);
    float acc = 0.f;
    for (int i = 0; i < 128; i++) {
        float4 a = p4[i], ww = w4[i];
        acc += a.x * ww.x + a.y * ww.y + a.z * ww.z + a.w * ww.w;
    }
    acc += b[o];
    out[t] = acc > 0.f ? acc : 0.f;
}

__global__ void fc2_kernel(const float* __restrict__ h, const float* __restrict__ w,
                           const float* __restrict__ b, float* __restrict__ out) {
    int n = blockIdx.x, tid = threadIdx.x;
    __shared__ float redw[40];
    const float4* h4 = (const float4*)(h + (size_t)n * 1024);
    float4 a = h4[tid];
    for (int o = 0; o < 10; o++) {
        const float4* w4 = (const float4*)(w + (size_t)o * 1024);
        float4 ww = w4[tid];
        float v = a.x * ww.x + a.y * ww.y + a.z * ww.z + a.w * ww.w;
        for (int off = 32; off > 0; off >>= 1) v += __shfl_down(v, off);
        if ((tid & 63) == 0) redw[o * 4 + (tid >> 6)] = v;
    }
    __syncthreads();
    if (tid < 10) {
        float s = redw[tid * 4] + redw[tid * 4 + 1] + redw[tid * 4 + 2] + redw[tid * 4 + 3] + b[tid];
        out[n * 10 + tid] = s;
    }
}

extern "C" void kernel_launch(void* const* d_in, const int* in_sizes, int n_in,
                              void* d_out, int out_size, void* d_ws, size_t ws_size,
                              hipStream_t stream) {
    const float* x   = (const float*)d_in[0];
    const float* w1  = (const float*)d_in[1];
    const float* s1  = (const float*)d_in[2];
    const float* b1  = (const float*)d_in[3];
    const float* w2  = (const float*)d_in[4];
    const float* s2  = (const float*)d_in[5];
    const float* b2  = (const float*)d_in[6];
    const float* w3  = (const float*)d_in[7];
    const float* s3  = (const float*)d_in[8];
    const float* b3  = (const float*)d_in[9];
    const float* fw1 = (const float*)d_in[10];
    const float* fs1 = (const float*)d_in[11];
    const float* fb1 = (const float*)d_in[12];
    const float* fw2 = (const float*)d_in[13];
    const float* fs2 = (const float*)d_in[14];
    const float* fb2 = (const float*)d_in[15];
    float* out = (float*)d_out;

    char* ws = (char*)d_ws;
    size_t off = 0;
    auto alloc = [&](size_t bytes) -> char* {
        char* p = ws + off;
        off = (off + bytes + 255) & ~(size_t)255;
        return p;
    };
    unsigned* hist   = (unsigned*)alloc(2ull * 5 * 65536 * 4);
    unsigned* histB  = hist + 5 * 65536;
    unsigned* selBin = (unsigned*)alloc(64);
    unsigned* rloc   = (unsigned*)alloc(64);
    unsigned* T      = (unsigned*)alloc(64);
    float* wm1  = (float*)alloc(3456ull * 4);
    float* wm2  = (float*)alloc(294912ull * 4);
    float* wm3  = (float*)alloc(1179648ull * 4);
    float* fwm1 = (float*)alloc(524288ull * 4);
    float* fwm2 = (float*)alloc(10240ull * 4);
    unsigned short* A2 = (unsigned short*)alloc(294912ull * 2);   // bf16 [9][256][128]
    unsigned short* A3 = (unsigned short*)alloc(1179648ull * 2);  // bf16 [9][512][256]
    unsigned short* h1 = (unsigned short*)alloc(33554432ull * 2); // bf16 64x128x64x64
    unsigned short* h2 = (unsigned short*)alloc(16777216ull * 2); // bf16 64x256x32x32
    float* pooled = (float*)alloc(32768ull * 4);                  // 64x512
    float* fc1h   = (float*)alloc(65536ull * 4);                  // 64x1024
    if (off > ws_size) return;

    (void)hipMemsetAsync(hist, 0, 2ull * 5 * 65536 * 4, stream);
    (void)hipMemsetAsync(pooled, 0, 32768ull * 4, stream);

    int gs = (STOT + 255) / 256;
    hist_pass1<<<gs, 256, 0, stream>>>(s1, s2, s3, fs1, fs2, hist);
    radix_find<<<5, 256, 0, stream>>>(hist, selBin, rloc, T, 0);
    hist_pass2<<<gs, 256, 0, stream>>>(s1, s2, s3, fs1, fs2, selBin, histB);
    radix_find<<<5, 256, 0, stream>>>(histB, selBin, rloc, T, 1);
    mask_weights<<<gs, 256, 0, stream>>>(w1, w2, w3, fw1, fw2, s1, s2, s3, fs1, fs2, T,
                                         wm1, wm2, wm3, fwm1, fwm2);
    reorder_w<256, 128><<<128, 256, 0, stream>>>(wm2, A2);
    reorder_w<512, 256><<<512, 256, 0, stream>>>(wm3, A3);

    // conv1: 3->128, 64x64, stride 1, direct fp32 -> bf16 h1
    conv_direct<3, 64, 64, 128, 16, 16, 8>
        <<<dim3(2, 2, 64 * 16), 256, 0, stream>>>(x, wm1, b1, h1);
    // conv2: 128->256, 64x64 -> 32x32, MFMA. tiles: 8 pixel-tiles x 2 k-tiles x 64 n
    conv_mfma<128, 64, 64, 256, 4, 32, false>
        <<<dim3(8, 2, 64), 256, 0, stream>>>(h1, A2, b2, h2);
    // conv3: 256->512, 32x32 -> 16x16, MFMA + fused GAP (atomic into pooled)
    conv_mfma<256, 32, 32, 512, 8, 16, true>
        <<<dim3(2, 4, 64), 256, 0, stream>>>(h2, A3, b3, pooled);

    fc1_kernel<<<256, 256, 0, stream>>>(pooled, fwm1, fb1, fc1h);
    fc2_kernel<<<64, 256, 0, stream>>>(fc1h, fwm2, fb2, out);
}

// Round 5
// 467.149 us; speedup vs baseline: 9.4984x; 2.0290x over previous
//
#include <hip/hip_runtime.h>
#include <stdint.h>

// ---------------------------------------------------------------------------
// Net_27891517620298: edge-popup supermask CNN forward.
// R4: selection via 4-pass 8-bit LDS-privatized radix select (replaces the
// global-atomic 16-bit histogram that serialized on hot exponent bins).
// Convs: conv1 direct fp32 -> bf16; conv2/conv3 bf16 implicit-GEMM MFMA.
// ---------------------------------------------------------------------------

typedef __attribute__((ext_vector_type(8))) short short8;
typedef __attribute__((ext_vector_type(4))) float floatx4;

__device__ __forceinline__ unsigned short f2bf(float f) {
    unsigned u = __float_as_uint(f);
    u += 0x7fffu + ((u >> 16) & 1u);   // round-to-nearest-even
    return (unsigned short)(u >> 16);
}

// ---------------- exact top-k selection: 4-pass 8-bit radix -----------------
constexpr unsigned CUM0 = 3456u;
constexpr unsigned CUM1 = 298368u;
constexpr unsigned CUM2 = 1478016u;
constexpr unsigned CUM3 = 2002304u;
constexpr unsigned STOT = 2012544u;
constexpr int NBH = 128;   // partial-histogram blocks

__device__ __forceinline__ int find_tensor(unsigned idx, unsigned& li) {
    if (idx < CUM0) { li = idx;        return 0; }
    if (idx < CUM1) { li = idx - CUM0; return 1; }
    if (idx < CUM2) { li = idx - CUM1; return 2; }
    if (idx < CUM3) { li = idx - CUM2; return 3; }
    li = idx - CUM3; return 4;
}

// Pass p bins: p<3 -> (key >> (23-8p)) & 255 ; p==3 -> key & 127.
// Filter: (key >> (31-8p)) == P[t]  (p==0: key>>31==0 always, P ignored).
// Per-wave LDS histograms -> per-block global partials (no atomics).
__global__ __launch_bounds__(256) void hist8(const float* __restrict__ s0,
                                             const float* __restrict__ s1,
                                             const float* __restrict__ s2,
                                             const float* __restrict__ s3,
                                             const float* __restrict__ s4,
                                             const unsigned* __restrict__ P,
                                             unsigned* __restrict__ partials, int pass) {
    __shared__ unsigned lh[4 * 1280];
    const int tid = threadIdx.x;
    const int wv = tid >> 6;
    for (int i = tid; i < 4 * 1280; i += 256) lh[i] = 0;
    __syncthreads();

    const int hi_sh = 31 - 8 * pass;
    const int bin_sh = 23 - 8 * pass;
    unsigned pref[5];
    #pragma unroll
    for (int t = 0; t < 5; t++) pref[t] = pass ? P[t] : 0u;

    for (unsigned idx = blockIdx.x * 256u + tid; idx < STOT; idx += NBH * 256u) {
        unsigned li; int t = find_tensor(idx, li);
        const float* sp = t == 0 ? s0 : t == 1 ? s1 : t == 2 ? s2 : t == 3 ? s3 : s4;
        unsigned key = __float_as_uint(sp[li]) & 0x7fffffffu;
        if ((key >> hi_sh) == pref[t]) {
            unsigned bin = (pass == 3) ? (key & 127u) : ((key >> bin_sh) & 255u);
            atomicAdd(&lh[wv * 1280 + (unsigned)t * 256u + bin], 1u);
        }
    }
    __syncthreads();
    for (int i = tid; i < 1280; i += 256)
        partials[(size_t)blockIdx.x * 1280 + i] =
            lh[i] + lh[1280 + i] + lh[2560 + i] + lh[3840 + i];
}

// One block per tensor: sum partials, locate the bin containing `target`,
// accumulate prefix. After pass 3, P[t] is the full 31-bit threshold.
__global__ __launch_bounds__(256) void find8(const unsigned* __restrict__ partials,
                                             unsigned* __restrict__ P,
                                             unsigned* __restrict__ targ, int pass) {
    const int t = blockIdx.x;
    const int tid = threadIdx.x;
    __shared__ unsigned bins[256];
    unsigned s = 0;
    for (int b = 0; b < NBH; b++) s += partials[(size_t)b * 1280 + t * 256 + tid];
    bins[tid] = s;
    __syncthreads();
    if (tid == 0) {
        unsigned n = t == 0 ? 3456u : t == 1 ? 294912u : t == 2 ? 1179648u
                   : t == 3 ? 524288u : 10240u;
        unsigned target = (pass == 0) ? (n >> 1) : targ[t];
        unsigned cum = 0; int b = 0;
        for (; b < 256; b++) { unsigned c = bins[b]; if (cum + c > target) break; cum += c; }
        targ[t] = target - cum;
        unsigned prev = (pass == 0) ? 0u : P[t];
        P[t] = (prev << ((pass == 3) ? 7 : 8)) | (unsigned)b;
    }
}

// wm = (|s| bits >= T) ? w : 0 for all 5 weight tensors
__global__ void mask_weights(const float* __restrict__ w0, const float* __restrict__ w1,
                             const float* __restrict__ w2, const float* __restrict__ w3,
                             const float* __restrict__ w4,
                             const float* __restrict__ s0, const float* __restrict__ s1,
                             const float* __restrict__ s2, const float* __restrict__ s3,
                             const float* __restrict__ s4,
                             const unsigned* __restrict__ T,
                             float* __restrict__ m0, float* __restrict__ m1,
                             float* __restrict__ m2, float* __restrict__ m3,
                             float* __restrict__ m4) {
    unsigned idx = blockIdx.x * 256u + threadIdx.x;
    if (idx >= STOT) return;
    unsigned li; int t = find_tensor(idx, li);
    const float* sp = t == 0 ? s0 : t == 1 ? s1 : t == 2 ? s2 : t == 3 ? s3 : s4;
    const float* wp = t == 0 ? w0 : t == 1 ? w1 : t == 2 ? w2 : t == 3 ? w3 : w4;
    float*       mp = t == 0 ? m0 : t == 1 ? m1 : t == 2 ? m2 : t == 3 ? m3 : m4;
    unsigned key = __float_as_uint(sp[li]) & 0x7fffffffu;
    mp[li] = (key >= T[t]) ? wp[li] : 0.f;
}

// reorder masked fp32 weights [k][c][3][3] -> bf16 A[e][k][c]
template <int KOUT, int CIN>
__global__ void reorder_w(const float* __restrict__ wm, unsigned short* __restrict__ A) {
    int t = blockIdx.x * 256 + threadIdx.x;
    if (t >= KOUT * CIN) return;
    int k = t / CIN, c = t % CIN;
    #pragma unroll
    for (int e = 0; e < 9; e++)
        A[((size_t)e * KOUT + k) * CIN + c] = f2bf(wm[(size_t)t * 9 + e]);
}

// ---------------- conv1: direct 3x3 fp32, bf16 output -----------------------
template <int C, int H, int W, int K, int TX, int TY, int KT>
__global__ __launch_bounds__(TX* TY) void conv_direct(const float* __restrict__ in,
                                                      const float* __restrict__ wm,
                                                      const float* __restrict__ bias,
                                                      unsigned short* __restrict__ out) {
    constexpr int TILW = TX * 2, TILH = TY * 2;
    constexpr int ITW = TILW + 2, ITH = TILH + 2;
    constexpr int NTHREADS = TX * TY;
    constexpr int NLOAD = (ITH * ITW + NTHREADS - 1) / NTHREADS;
    constexpr int KG = K / KT;

    __shared__ float sIn[ITH * ITW];
    __shared__ float sW[9 * KT];

    const int tid = threadIdx.x;
    const int tx = tid % TX, ty = tid / TX;
    const int kg = blockIdx.z % KG, n = blockIdx.z / KG;
    const int ox0 = blockIdx.x * TILW, oy0 = blockIdx.y * TILH;
    const int ix0 = ox0 - 1, iy0 = oy0 - 1;

    const float* inN = in + (size_t)n * C * H * W;
    const float* wkg = wm + (size_t)kg * KT * C * 9;

    int goff[NLOAD];
    #pragma unroll
    for (int i = 0; i < NLOAD; i++) {
        int idx = tid + i * NTHREADS;
        if (idx < ITH * ITW) {
            int r = idx / ITW, col = idx % ITW;
            int gy = iy0 + r, gx = ix0 + col;
            goff[i] = (gy >= 0 && gy < H && gx >= 0 && gx < W) ? (gy * W + gx) : -1;
        } else goff[i] = -2;
    }

    float acc[2][2][KT];
    #pragma unroll
    for (int py = 0; py < 2; py++)
        #pragma unroll
        for (int px = 0; px < 2; px++)
            #pragma unroll
            for (int j = 0; j < KT; j++) acc[py][px][j] = 0.f;

    for (int c = 0; c < C; c++) {
        const float* inC = inN + (size_t)c * H * W;
        #pragma unroll
        for (int i = 0; i < NLOAD; i++) {
            int g = goff[i];
            if (g >= -1) sIn[tid + i * NTHREADS] = (g >= 0) ? inC[g] : 0.f;
        }
        for (int i = tid; i < 9 * KT; i += NTHREADS) {
            int e = i / KT, j = i % KT;
            sW[i] = wkg[j * C * 9 + c * 9 + e];
        }
        __syncthreads();

        float vin[4][4];
        const float* base = &sIn[(ty * 2) * ITW + tx * 2];
        #pragma unroll
        for (int r = 0; r < 4; r++)
            #pragma unroll
            for (int cc = 0; cc < 4; cc++) vin[r][cc] = base[r * ITW + cc];

        #pragma unroll
        for (int e = 0; e < 9; e++) {
            const int dy = e / 3, dx = e % 3;
            #pragma unroll
            for (int j = 0; j < KT; j++) {
                float wv = sW[e * KT + j];
                #pragma unroll
                for (int py = 0; py < 2; py++)
                    #pragma unroll
                    for (int px = 0; px < 2; px++)
                        acc[py][px][j] = fmaf(vin[py + dy][px + dx], wv, acc[py][px][j]);
            }
        }
        __syncthreads();
    }

    #pragma unroll
    for (int j = 0; j < KT; j++) {
        float b = bias[kg * KT + j];
        #pragma unroll
        for (int py = 0; py < 2; py++)
            #pragma unroll
            for (int px = 0; px < 2; px++) {
                int oy = oy0 + ty * 2 + py, ox = ox0 + tx * 2 + px;
                float v = acc[py][px][j] + b;
                v = v > 0.f ? v : 0.f;
                out[(((size_t)n * K + kg * KT + j) * H + oy) * W + ox] = f2bf(v);
            }
    }
}

// ---------------- conv2/conv3: bf16 implicit GEMM on MFMA 16x16x32 ----------
template <int C, int H, int W, int KOUT, int TOY, int TOX, bool POOL>
__global__ __launch_bounds__(256) void conv_mfma(const unsigned short* __restrict__ in,
                                                 const unsigned short* __restrict__ A,
                                                 const float* __restrict__ bias,
                                                 void* __restrict__ outv) {
    constexpr int OH = H / 2, OW = W / 2;
    constexpr int RH = 2 * TOY + 1, IW = 2 * TOX + 1;
    constexpr int HWv = H * W;
    constexpr int NC = C / 32;
    constexpr int NSLOT = RH * IW * 4;
    constexpr int SLMAX = (NSLOT + 255) / 256;

    __shared__ unsigned short sIn[RH * IW * 40];
    __shared__ unsigned short sWt[128 * 40];

    const int tid = threadIdx.x;
    const int lane = tid & 63;
    const int wv = tid >> 6;
    const int l15 = lane & 15;
    const int quad = lane >> 4;
    const int pt = blockIdx.x, kb = blockIdx.y, n = blockIdx.z;
    const int k0 = kb * 128;
    const int oy0 = pt * TOY;
    const int g0y = 2 * oy0 - 1;

    int soff[SLMAX], slds[SLMAX];
    #pragma unroll
    for (int i = 0; i < SLMAX; i++) {
        int s = tid + i * 256;
        if (s < NSLOT) {
            int ix = s % IW; int t2 = s / IW; int iy = t2 % RH; int c8 = t2 / RH;
            int gy = g0y + iy, gx = ix - 1;
            slds[i] = (iy * IW + ix) * 40 + c8 * 8;
            soff[i] = (gy >= 0 && gy < H && gx >= 0) ? (c8 * 8 * HWv + gy * W + gx) : -1;
        } else { soff[i] = -2; slds[i] = 0; }
    }

    int pB[8];
    #pragma unroll
    for (int fn = 0; fn < 8; fn++) {
        int p = fn * 16 + l15;
        int oyl = p / TOX, oxl = p % TOX;
        pB[fn] = (oyl * 2 * IW + oxl * 2) * 40 + quad * 8;
    }
    const int mw = wv * 32;

    floatx4 acc[2][8];
    #pragma unroll
    for (int fm = 0; fm < 2; fm++)
        #pragma unroll
        for (int fn = 0; fn < 8; fn++) acc[fm][fn] = (floatx4){0.f, 0.f, 0.f, 0.f};

    const int inN = n * C * HWv;

    for (int cc = 0; cc < NC; cc++) {
        __syncthreads();
        const int cbase = inN + cc * 32 * HWv;
        #pragma unroll
        for (int i = 0; i < SLMAX; i++) {
            int so = soff[i];
            if (so >= 0) {
                short8 v;
                #pragma unroll
                for (int j = 0; j < 8; j++) v[j] = (short)in[cbase + so + j * HWv];
                *(short8*)&sIn[slds[i]] = v;
            } else if (so == -1 && cc == 0) {
                *(short8*)&sIn[slds[i]] = (short8){0, 0, 0, 0, 0, 0, 0, 0};
            }
        }
        for (int e = 0; e < 9; e++) {
            __syncthreads();
            {
                const unsigned short* src = A + ((size_t)e * KOUT + k0) * C + cc * 32;
                #pragma unroll
                for (int i = 0; i < 2; i++) {
                    int s = tid + i * 256;
                    int k = s >> 2, c8 = s & 3;
                    short8 v = *(const short8*)(src + k * C + c8 * 8);
                    *(short8*)&sWt[k * 40 + c8 * 8] = v;
                }
            }
            __syncthreads();
            const int dy = e / 3, dx = e - dy * 3;
            const int boff = (dy * IW + dx) * 40;
            short8 afr[2], bfr[8];
            #pragma unroll
            for (int fm = 0; fm < 2; fm++)
                afr[fm] = *(const short8*)&sWt[(mw + fm * 16 + l15) * 40 + quad * 8];
            #pragma unroll
            for (int fn = 0; fn < 8; fn++)
                bfr[fn] = *(const short8*)&sIn[pB[fn] + boff];
            #pragma unroll
            for (int fm = 0; fm < 2; fm++)
                #pragma unroll
                for (int fn = 0; fn < 8; fn++)
                    acc[fm][fn] = __builtin_amdgcn_mfma_f32_16x16x32_bf16(
                        afr[fm], bfr[fn], acc[fm][fn], 0, 0, 0);
        }
    }

    if (!POOL) {
        unsigned short* out = (unsigned short*)outv;
        #pragma unroll
        for (int fm = 0; fm < 2; fm++) {
            #pragma unroll
            for (int reg = 0; reg < 4; reg++) {
                int k = k0 + mw + fm * 16 + quad * 4 + reg;
                float b = bias[k];
                #pragma unroll
                for (int fn = 0; fn < 8; fn++) {
                    int p = fn * 16 + l15;
                    int oy = oy0 + p / TOX, ox = p % TOX;
                    float v = acc[fm][fn][reg] + b;
                    v = v > 0.f ? v : 0.f;
                    out[((size_t)(n * KOUT + k) * OH + oy) * OW + ox] = f2bf(v);
                }
            }
        }
    } else {
        float* out = (float*)outv;
        #pragma unroll
        for (int fm = 0; fm < 2; fm++) {
            #pragma unroll
            for (int reg = 0; reg < 4; reg++) {
                int k = k0 + mw + fm * 16 + quad * 4 + reg;
                float b = bias[k];
                float s = 0.f;
                #pragma unroll
                for (int fn = 0; fn < 8; fn++) {
                    float v = acc[fm][fn][reg] + b;
                    s += v > 0.f ? v : 0.f;
                }
                s += __shfl_xor(s, 1); s += __shfl_xor(s, 2);
                s += __shfl_xor(s, 4); s += __shfl_xor(s, 8);
                if (l15 == 0) atomicAdd(&out[n * KOUT + k], s * (1.0f / (OH * OW)));
            }
        }
    }
}

// ---------------- FCs (fp32, tiny) -----------------------------------------
__global__ void fc1_kernel(const float* __restrict__ pooled, const float* __restrict__ w,
                           const float* __restrict__ b, float* __restrict__ out) {
    int t = blockIdx.x * 256 + threadIdx.x;
    int o = t & 1023, n = t >> 10;
    const float4* w4 = (const float4*)(w + (size_t)o * 512);
    const float4* p4 = (const float4*)(pooled + (size_t)n * 512);
    float acc = 0.f;
    for (int i = 0; i < 128; i++) {
        float4 a = p4[i], ww = w4[i];
        acc += a.x * ww.x + a.y * ww.y + a.z * ww.z + a.w * ww.w;
    }
    acc += b[o];
    out[t] = acc > 0.f ? acc : 0.f;
}

__global__ void fc2_kernel(const float* __restrict__ h, const float* __restrict__ w,
                           const float* __restrict__ b, float* __restrict__ out) {
    int n = blockIdx.x, tid = threadIdx.x;
    __shared__ float redw[40];
    const float4* h4 = (const float4*)(h + (size_t)n * 1024);
    float4 a = h4[tid];
    for (int o = 0; o < 10; o++) {
        const float4* w4 = (const float4*)(w + (size_t)o * 1024);
        float4 ww = w4[tid];
        float v = a.x * ww.x + a.y * ww.y + a.z * ww.z + a.w * ww.w;
        for (int off = 32; off > 0; off >>= 1) v += __shfl_down(v, off);
        if ((tid & 63) == 0) redw[o * 4 + (tid >> 6)] = v;
    }
    __syncthreads();
    if (tid < 10) {
        float s = redw[tid * 4] + redw[tid * 4 + 1] + redw[tid * 4 + 2] + redw[tid * 4 + 3] + b[tid];
        out[n * 10 + tid] = s;
    }
}

extern "C" void kernel_launch(void* const* d_in, const int* in_sizes, int n_in,
                              void* d_out, int out_size, void* d_ws, size_t ws_size,
                              hipStream_t stream) {
    const float* x   = (const float*)d_in[0];
    const float* w1  = (const float*)d_in[1];
    const float* s1  = (const float*)d_in[2];
    const float* b1  = (const float*)d_in[3];
    const float* w2  = (const float*)d_in[4];
    const float* s2  = (const float*)d_in[5];
    const float* b2  = (const float*)d_in[6];
    const float* w3  = (const float*)d_in[7];
    const float* s3  = (const float*)d_in[8];
    const float* b3  = (const float*)d_in[9];
    const float* fw1 = (const float*)d_in[10];
    const float* fs1 = (const float*)d_in[11];
    const float* fb1 = (const float*)d_in[12];
    const float* fw2 = (const float*)d_in[13];
    const float* fs2 = (const float*)d_in[14];
    const float* fb2 = (const float*)d_in[15];
    float* out = (float*)d_out;

    char* ws = (char*)d_ws;
    size_t off = 0;
    auto alloc = [&](size_t bytes) -> char* {
        char* p = ws + off;
        off = (off + bytes + 255) & ~(size_t)255;
        return p;
    };
    unsigned* partials = (unsigned*)alloc((size_t)NBH * 1280 * 4);
    unsigned* P        = (unsigned*)alloc(64);
    unsigned* targ     = (unsigned*)alloc(64);
    float* wm1  = (float*)alloc(3456ull * 4);
    float* wm2  = (float*)alloc(294912ull * 4);
    float* wm3  = (float*)alloc(1179648ull * 4);
    float* fwm1 = (float*)alloc(524288ull * 4);
    float* fwm2 = (float*)alloc(10240ull * 4);
    unsigned short* A2 = (unsigned short*)alloc(294912ull * 2);   // bf16 [9][256][128]
    unsigned short* A3 = (unsigned short*)alloc(1179648ull * 2);  // bf16 [9][512][256]
    unsigned short* h1 = (unsigned short*)alloc(33554432ull * 2); // bf16 64x128x64x64
    unsigned short* h2 = (unsigned short*)alloc(16777216ull * 2); // bf16 64x256x32x32
    float* pooled = (float*)alloc(32768ull * 4);                  // 64x512
    float* fc1h   = (float*)alloc(65536ull * 4);                  // 64x1024
    if (off > ws_size) return;

    (void)hipMemsetAsync(pooled, 0, 32768ull * 4, stream);

    // 4-pass radix select (no histogram memset needed; partials fully written)
    for (int pass = 0; pass < 4; pass++) {
        hist8<<<NBH, 256, 0, stream>>>(s1, s2, s3, fs1, fs2, P, partials, pass);
        find8<<<5, 256, 0, stream>>>(partials, P, targ, pass);
    }
    int gs = (STOT + 255) / 256;
    mask_weights<<<gs, 256, 0, stream>>>(w1, w2, w3, fw1, fw2, s1, s2, s3, fs1, fs2, P,
                                         wm1, wm2, wm3, fwm1, fwm2);
    reorder_w<256, 128><<<128, 256, 0, stream>>>(wm2, A2);
    reorder_w<512, 256><<<512, 256, 0, stream>>>(wm3, A3);

    // conv1: 3->128, 64x64, stride 1, direct fp32 -> bf16 h1
    conv_direct<3, 64, 64, 128, 16, 16, 8>
        <<<dim3(2, 2, 64 * 16), 256, 0, stream>>>(x, wm1, b1, h1);
    // conv2: 128->256, 64x64 -> 32x32, MFMA
    conv_mfma<128, 64, 64, 256, 4, 32, false>
        <<<dim3(8, 2, 64), 256, 0, stream>>>(h1, A2, b2, h2);
    // conv3: 256->512, 32x32 -> 16x16, MFMA + fused GAP
    conv_mfma<256, 32, 32, 512, 8, 16, true>
        <<<dim3(2, 4, 64), 256, 0, stream>>>(h2, A3, b3, pooled);

    fc1_kernel<<<256, 256, 0, stream>>>(pooled, fwm1, fb1, fc1h);
    fc2_kernel<<<64, 256, 0, stream>>>(fc1h, fwm2, fb2, out);
}